// Round 10
// baseline (95.342 us; speedup 1.0000x reference)
//
#include <hip/hip_runtime.h>
#include <math.h>

// Problem constants: [N, L, H, D] = [4, 8192, 8, 64], Dv = 64, fp32 in/out.
#define N_    4
#define L_    8192
#define H_    8
#define NH_   32           // N*H
#define CHK   64           // chunk length
#define NC_   128          // chunks per (n,h)
#define ROWF  512          // H_*D_ floats between consecutive l
#define EPSF  1e-6f

typedef __attribute__((ext_vector_type(8))) short bf16x8;   // 8 bf16 = 4 VGPRs
typedef __attribute__((ext_vector_type(4))) float f32x4;
typedef __attribute__((ext_vector_type(4))) unsigned short us4;

__device__ __forceinline__ float fmap(float x) { return x > 0.f ? x + 1.f : __expf(x); }

__device__ __forceinline__ unsigned short f2bf(float x) {
  unsigned u = __float_as_uint(x);
  u += 0x7FFFu + ((u >> 16) & 1u);       // round-to-nearest-even
  return (unsigned short)(u >> 16);
}
__device__ __forceinline__ float bf2f(unsigned short u) {
  return __uint_as_float(((unsigned)u) << 16);
}

// Swizzled ushort index into a row-major [64] bf16 tile (row stride 128 B).
__device__ __forceinline__ int sidx(int row, int col) {
  return row * 64 + (col ^ ((row & 7) << 3));
}

__device__ __forceinline__ f32x4 MFMA(bf16x8 a, bf16x8 b, f32x4 c) {
  return __builtin_amdgcn_mfma_f32_16x16x32_bf16(a, b, c, 0, 0, 0);
}

// global -> LDS DMA, 16 B per lane (wave-uniform LDS base + lane*16).
__device__ __forceinline__ void gload_lds16(const void* g, void* l) {
  __builtin_amdgcn_global_load_lds(
      (const __attribute__((address_space(1))) void*)g,
      (__attribute__((address_space(3))) void*)l, 16, 0, 0);
}

// ---------------- Pass A: per-chunk totals T_c and K column-sums (DMA-staged) ----------------
__global__ __launch_bounds__(256) void k_chunk_tot(const float* __restrict__ keys,
                                                   const float* __restrict__ values,
                                                   unsigned short* __restrict__ Tws,
                                                   float* __restrict__ Kcs) {
  __shared__ __align__(16) float Raw[8192];   // 32 KB: K raw [0:4096), V raw [4096:8192)
  __shared__ float kacc[64];
  unsigned short* Kt = (unsigned short*)Raw;           // bytes [0,8K): K^T bf16 (after restage)
  unsigned short* Vt = (unsigned short*)(Raw + 4096);  // bytes [16K,24K): V^T bf16
  unsigned short* Tt = (unsigned short*)(Raw + 6144);  // bytes [24K,32K): T tile
  const int bid = blockIdx.x;             // nh*NC_ + c
  const int nh = bid / NC_, c = bid % NC_;
  const int n = nh / H_, h = nh % H_;
  const int tid = threadIdx.x;
  const int lane = tid & 63;
  const int wv = tid >> 6;
  const int lane15 = lane & 15, lg = lane >> 4;
  const int arow = wv * 16 + lane15;      // e-row for the V fragment

  if (tid < 64) kacc[tid] = 0.f;

  // ---- DMA staging: wave wv covers rows [wv*16, wv*16+16), 4 rows per instr ----
  {
    const size_t rowbase = (size_t)(n * L_ + c * CHK);
    const size_t coff = (size_t)h * 64 + (lane & 15) * 4;
#pragma unroll
    for (int b = 0; b < 4; ++b) {
      const int s4 = wv * 16 + b * 4;
      const size_t g = (rowbase + s4 + (lane >> 4)) * ROWF + coff;
      gload_lds16(&keys[g],   &Raw[s4 * 64]);
      gload_lds16(&values[g], &Raw[4096 + s4 * 64]);
    }
  }
  __syncthreads();  // B0: DMA drained (vmcnt), raw tiles complete

  // ---- reg-stage this thread's slices, then repack as transposed bf16 ----
  const int s = tid >> 2, dg = tid & 3;   // row s, col-quarter dg
  f32x4 kq[4], vq[4];
#pragma unroll
  for (int q = 0; q < 4; ++q) {
    kq[q] = *(const f32x4*)&Raw[s * 64 + dg * 16 + q * 4];
    vq[q] = *(const f32x4*)&Raw[4096 + s * 64 + dg * 16 + q * 4];
  }
  __syncthreads();  // B1: all raw reads done; regions reusable
#pragma unroll
  for (int q = 0; q < 4; ++q) {
#pragma unroll
    for (int j = 0; j < 4; ++j) {
      const int dd = dg * 16 + q * 4 + j;
      Kt[sidx(dd, s)] = f2bf(fmap(kq[q][j]));
      Vt[sidx(dd, s)] = f2bf(vq[q][j]);
    }
  }
  __syncthreads();  // B2: bf16 tiles built

  // column sums from Kt (row d = column d of K), 4 adders per column
  {
    const int d2 = tid & 63, sg2 = tid >> 6;
    float ksum = 0.f;
#pragma unroll
    for (int i4 = 0; i4 < 4; ++i4) {
      const us4 w = *(const us4*)&Kt[sidx(d2, sg2 * 16 + i4 * 4)];
#pragma unroll
      for (int j = 0; j < 4; ++j) ksum += bf2f(w[j]);
    }
    atomicAdd(&kacc[d2], ksum);
  }

  // swapped MFMA: lane holds T[e = arow][d = nt*16 + lg*4 + r]
  const bf16x8 av0 = *(const bf16x8*)&Vt[sidx(arow, lg * 8)];
  const bf16x8 av1 = *(const bf16x8*)&Vt[sidx(arow, (lg + 4) * 8)];
  us4 tf[4];
#pragma unroll
  for (int nt = 0; nt < 4; ++nt) {
    const int brow = nt * 16 + lane15;   // d-window
    f32x4 acc = {0.f, 0.f, 0.f, 0.f};
    acc = MFMA(*(const bf16x8*)&Kt[sidx(brow, lg * 8)], av0, acc);
    acc = MFMA(*(const bf16x8*)&Kt[sidx(brow, (lg + 4) * 8)], av1, acc);
#pragma unroll
    for (int r = 0; r < 4; ++r) tf[nt][r] = f2bf(acc[r]);
  }
  // scatter frags into Tt (disjoint region; no barrier needed before this)
#pragma unroll
  for (int nt = 0; nt < 4; ++nt)
    *(us4*)&Tt[sidx(arow, nt * 16 + lg * 4)] = tf[nt];
  __syncthreads();  // B3: Tt complete; kacc atomics drained

  {
    unsigned short* Tp = Tws + (size_t)bid * 4096;
#pragma unroll
    for (int it = 0; it < 2; ++it) {
      const int i8 = (tid + it * 256) * 8;
      *(uint4*)&Tp[i8] = *(const uint4*)&Tt[i8];
    }
  }
  if (tid < 64) Kcs[(size_t)bid * 64 + tid] = kacc[tid];
}

// ---------------- Pass B: in-place exclusive prefix over chunks (depth 32, 4-wide) ----------------
__global__ __launch_bounds__(256) void k_scan(unsigned short* __restrict__ Tws,
                                              float* __restrict__ Kcs) {
  const int tid = threadIdx.x;
  if (blockIdx.x < 512) {
    const int gid = blockIdx.x * 256 + tid;          // 0 .. 131071
    const int nh = gid >> 12, de = gid & 4095;
    unsigned short* p = Tws + (size_t)nh * NC_ * 4096 + de;
    float run = 0.f;
    for (int s = 0; s < 32; ++s) {
      const float x0 = bf2f(p[(size_t)(s * 4 + 0) * 4096]);
      const float x1 = bf2f(p[(size_t)(s * 4 + 1) * 4096]);
      const float x2 = bf2f(p[(size_t)(s * 4 + 2) * 4096]);
      const float x3 = bf2f(p[(size_t)(s * 4 + 3) * 4096]);
      p[(size_t)(s * 4 + 0) * 4096] = f2bf(run);
      p[(size_t)(s * 4 + 1) * 4096] = f2bf(run + x0);
      p[(size_t)(s * 4 + 2) * 4096] = f2bf(run + x0 + x1);
      p[(size_t)(s * 4 + 3) * 4096] = f2bf(run + x0 + x1 + x2);
      run += x0 + x1 + x2 + x3;
    }
  } else {
    const int gid = (blockIdx.x - 512) * 256 + tid;  // 0 .. 2047
    const int nh = gid >> 6, d = gid & 63;
    float* p = Kcs + (size_t)nh * NC_ * 64 + d;
    float run = 0.f;
    for (int s = 0; s < 32; ++s) {
      const float x0 = p[(size_t)(s * 4 + 0) * 64];
      const float x1 = p[(size_t)(s * 4 + 1) * 64];
      const float x2 = p[(size_t)(s * 4 + 2) * 64];
      const float x3 = p[(size_t)(s * 4 + 3) * 64];
      p[(size_t)(s * 4 + 0) * 64] = run;
      p[(size_t)(s * 4 + 1) * 64] = run + x0;
      p[(size_t)(s * 4 + 2) * 64] = run + x0 + x1;
      p[(size_t)(s * 4 + 3) * 64] = run + x0 + x1 + x2;
      run += x0 + x1 + x2 + x3;
    }
  }
}

// ---------------- Pass C: per-chunk output (DMA-staged) ----------------
__global__ __launch_bounds__(256) void k_output(const float* __restrict__ queries,
                                                const float* __restrict__ keys,
                                                const float* __restrict__ values,
                                                const unsigned short* __restrict__ Pws,
                                                const float* __restrict__ Kpre,
                                                float* __restrict__ out) {
  __shared__ __align__(16) float Raw[8192];            // 32 KB: K raw / V raw; later Ks/Vt
  __shared__ __align__(16) unsigned short St[4096];    // 8 KB, DMA'd (already swizzled image)
  __shared__ float kpre[64];
  unsigned short* Ks = (unsigned short*)Raw;           // bytes [0,8K): K bf16 rows; later attn
  unsigned short* Vt = (unsigned short*)(Raw + 4096);  // bytes [16K,24K): V^T bf16

  // XCD-aware swizzle: 4096 % 8 == 0 -> bijective
  const int wg = blockIdx.x;
  const int bid = (wg & 7) * (NH_ * NC_ / 8) + (wg >> 3);
  const int nh = bid / NC_, c = bid % NC_;
  const int n = nh / H_, h = nh % H_;
  const int tid = threadIdx.x;
  const int lane = tid & 63;
  const int wv = tid >> 6;
  const int lane15 = lane & 15, lg = lane >> 4;
  const int t0w = wv * 16;
  const int trow = t0w + lane15;          // this lane's attn/output row (wave-local)
  const int l0 = c * CHK;
  const size_t tb = (size_t)bid * 4096;

  // ---- DMA staging: K, V raw (4 instr each per wave), St (2 per wave) ----
  {
    const size_t rowbase = (size_t)(n * L_ + l0);
    const size_t coff = (size_t)h * 64 + (lane & 15) * 4;
#pragma unroll
    for (int b = 0; b < 4; ++b) {
      const int s4 = wv * 16 + b * 4;
      const size_t g = (rowbase + s4 + (lane >> 4)) * ROWF + coff;
      gload_lds16(&keys[g],   &Raw[s4 * 64]);
      gload_lds16(&values[g], &Raw[4096 + s4 * 64]);
    }
#pragma unroll
    for (int b = 0; b < 2; ++b) {
      const int u0 = wv * 1024 + b * 512;
      gload_lds16(&Pws[tb + u0 + lane * 8], &St[u0]);
    }
  }
  // Q fragments + kpre via normal loads (in flight across the barrier region)
  const size_t qg = ((size_t)(n * L_ + l0 + trow)) * ROWF + h * 64;
  const float4 q0 = *(const float4*)&queries[qg + lg * 8];
  const float4 q1 = *(const float4*)&queries[qg + lg * 8 + 4];
  const float4 q2 = *(const float4*)&queries[qg + 32 + lg * 8];
  const float4 q3 = *(const float4*)&queries[qg + 32 + lg * 8 + 4];
  const float kp = (tid < 64) ? Kpre[(size_t)bid * 64 + tid] : 0.f;
  __syncthreads();  // B0: DMA drained; raw + St complete

  // ---- reg-stage K/V slices, then repack ----
  const int s = tid >> 2, dg = tid & 3;
  f32x4 kq[4], vq[4];
#pragma unroll
  for (int q = 0; q < 4; ++q) {
    kq[q] = *(const f32x4*)&Raw[s * 64 + dg * 16 + q * 4];
    vq[q] = *(const f32x4*)&Raw[4096 + s * 64 + dg * 16 + q * 4];
  }
  __syncthreads();  // B1: raw reads done
#pragma unroll
  for (int q = 0; q < 4; ++q) {
    us4 wk;
#pragma unroll
    for (int j = 0; j < 4; ++j) {
      wk[j] = f2bf(fmap(kq[q][j]));
      Vt[sidx(dg * 16 + q * 4 + j, s)] = f2bf(vq[q][j]);   // transposed scatter
    }
    *(us4*)&Ks[sidx(s, dg * 16 + q * 4)] = wk;             // row-major
  }
  bf16x8 qf0, qf1;
  qf0[0] = (short)f2bf(fmap(q0.x)); qf0[1] = (short)f2bf(fmap(q0.y));
  qf0[2] = (short)f2bf(fmap(q0.z)); qf0[3] = (short)f2bf(fmap(q0.w));
  qf0[4] = (short)f2bf(fmap(q1.x)); qf0[5] = (short)f2bf(fmap(q1.y));
  qf0[6] = (short)f2bf(fmap(q1.z)); qf0[7] = (short)f2bf(fmap(q1.w));
  qf1[0] = (short)f2bf(fmap(q2.x)); qf1[1] = (short)f2bf(fmap(q2.y));
  qf1[2] = (short)f2bf(fmap(q2.z)); qf1[3] = (short)f2bf(fmap(q2.w));
  qf1[4] = (short)f2bf(fmap(q3.x)); qf1[5] = (short)f2bf(fmap(q3.y));
  qf1[6] = (short)f2bf(fmap(q3.z)); qf1[7] = (short)f2bf(fmap(q3.w));
  if (tid < 64) kpre[tid] = kp;
  __syncthreads();  // B2: bf16 tiles + kpre visible

  // ---- QK^T, swapped: lane holds attn[t = trow][s = nt*16 + lg*4 + r] ----
  f32x4 aT[4];
#pragma unroll
  for (int nt = 0; nt < 4; ++nt) {
    const int srow = nt * 16 + lane15;
    f32x4 a = {0.f, 0.f, 0.f, 0.f};
    a = MFMA(*(const bf16x8*)&Ks[sidx(srow, lg * 8)], qf0, a);
    a = MFMA(*(const bf16x8*)&Ks[sidx(srow, (lg + 4) * 8)], qf1, a);
    aT[nt] = a;
  }
  // zden inter-chunk term: in-register dot Q[trow] . kpre
  float zp = 0.f;
#pragma unroll
  for (int j = 0; j < 8; ++j) zp += bf2f((unsigned short)qf0[j]) * kpre[lg * 8 + j];
#pragma unroll
  for (int j = 0; j < 8; ++j) zp += bf2f((unsigned short)qf1[j]) * kpre[32 + lg * 8 + j];

  __syncthreads();  // B3: all waves' Ks reads done (Ks becomes the attn buffer)

  // ---- mask + rowsum + attn rows into Ks (wave-local rows) ----
  float rs = 0.f;
#pragma unroll
  for (int nt = 0; nt < 4; ++nt) {
    us4 w;
#pragma unroll
    for (int r = 0; r < 4; ++r) {
      const int sc = nt * 16 + lg * 4 + r;
      const float v = (sc <= trow) ? aT[nt][r] : 0.f;
      rs += v;
      w[r] = f2bf(v);
    }
    *(us4*)&Ks[sidx(trow, nt * 16 + lg * 4)] = w;
  }
  // denominator for row trow: reduce the 4 lg-partials; zv stays lane-local
  float den = rs + zp;
  den += __shfl_xor(den, 16);
  den += __shfl_xor(den, 32);
  const float zv = 1.f / (den + EPSF);

  // ---- out^T-frags: lane holds out[trow][e = nt*16 + lg*4 + r] -> float4 stores ----
  const bf16x8 af0 = *(const bf16x8*)&Ks[sidx(trow, lg * 8)];
  const bf16x8 af1 = *(const bf16x8*)&Ks[sidx(trow, 32 + lg * 8)];
  const size_t obase = ((size_t)(n * L_ + l0 + trow)) * ROWF + h * 64;
#pragma unroll
  for (int nt = 0; nt < 4; ++nt) {
    const int brow = nt * 16 + lane15;   // Vt/St row (e) window
    f32x4 o = {0.f, 0.f, 0.f, 0.f};
    o = MFMA(*(const bf16x8*)&Vt[sidx(brow, lg * 8)], af0, o);
    o = MFMA(*(const bf16x8*)&Vt[sidx(brow, (lg + 4) * 8)], af1, o);
    o = MFMA(*(const bf16x8*)&St[sidx(brow, lg * 8)], qf0, o);
    o = MFMA(*(const bf16x8*)&St[sidx(brow, (lg + 4) * 8)], qf1, o);
    const float4 w = make_float4(o[0] * zv, o[1] * zv, o[2] * zv, o[3] * zv);
    *(float4*)&out[obase + nt * 16 + lg * 4] = w;
  }
}

extern "C" void kernel_launch(void* const* d_in, const int* in_sizes, int n_in,
                              void* d_out, int out_size, void* d_ws, size_t ws_size,
                              hipStream_t stream) {
  const float* queries = (const float*)d_in[0];
  const float* keys    = (const float*)d_in[1];
  const float* values  = (const float*)d_in[2];
  float* out = (float*)d_out;

  // workspace layout:
  //  Tws [NH_*NC_][4096] bf16  (chunk totals -> in-place exclusive prefixes; swizzled image)
  //  Kcs [NH_*NC_][64]   fp32  (chunk colsums -> exclusive prefixes)
  const size_t t_elems = (size_t)NH_ * NC_ * 4096;
  const size_t k_elems = (size_t)NH_ * NC_ * 64;
  if (ws_size < t_elems * 2 + k_elems * 4) return;
  unsigned short* Tws = (unsigned short*)d_ws;
  float* Kcs = (float*)(Tws + t_elems);

  hipLaunchKernelGGL(k_chunk_tot, dim3(NH_ * NC_), dim3(256), 0, stream, keys, values, Tws, Kcs);
  hipLaunchKernelGGL(k_scan, dim3(512 + 8), dim3(256), 0, stream, Tws, Kcs);
  hipLaunchKernelGGL(k_output, dim3(NH_ * NC_), dim3(256), 0, stream,
                     queries, keys, values, Tws, Kcs, out);
}